// Round 11
// baseline (697.982 us; speedup 1.0000x reference)
//
#include <hip/hip_runtime.h>
#include <cstdint>

#define RES 4096
#define N_CELLS (RES*RES)

// ============== register-marching temporal-blocked Jacobi ==============
// 2 launches x T=10 steps. Thread owns 4-row x float4-col strip in registers.
// packed decoded ONCE into (s, m): step update = fmaf(s, up+dn+lf+rt, m).
// 768 thr = 24 strips x 32 cols; tile 128x96 -> output 104x72.
#define MT_OW 104
#define MT_OH 72
#define MT_HH 12
#define MT_HV 12
#define MT_NSTRIP 24
#define MT_THR 768
#define MT_GX 40                  // ceil(4096/104)
#define MT_GY 57                  // ceil(4096/72)

__device__ __forceinline__ void mdecode(const uint4 pp, float4& ss, float4& mm)
{
    ss.x = (pp.x >> 31) ? 0.f : 0.25f;  mm.x = __uint_as_float(pp.x & 0x7fffffffu);
    ss.y = (pp.y >> 31) ? 0.f : 0.25f;  mm.y = __uint_as_float(pp.y & 0x7fffffffu);
    ss.z = (pp.z >> 31) ? 0.f : 0.25f;  mm.z = __uint_as_float(pp.z & 0x7fffffffu);
    ss.w = (pp.w >> 31) ? 0.f : 0.25f;  mm.w = __uint_as_float(pp.w & 0x7fffffffu);
}

__device__ __forceinline__ float4 jrow2(float4 up, float4 dn, const float4 cur,
                                        const float4 s, const float4 m,
                                        const int gr, const int gc)
{
    float lf = __shfl_up(cur.w, 1);        // adjacent lane = adjacent column
    float rt = __shfl_down(cur.x, 1);
    lf = (gc == 0)         ? cur.x : lf;   // image-left replicate (bypasses shfl)
    rt = (gc + 3 == RES-1) ? cur.w : rt;   // image-right replicate
    if (gr <= 0)       up = cur;           // image-top replicate; gr<0 garbage rows
    if (gr >= RES - 1) dn = cur;           // image-bottom replicate; OOB garbage
    float4 nv;
    nv.x = fmaf(s.x, up.x + dn.x + lf    + cur.y, m.x);
    nv.y = fmaf(s.y, up.y + dn.y + cur.x + cur.z, m.y);
    nv.z = fmaf(s.z, up.z + dn.z + cur.y + cur.w, m.z);
    nv.w = fmaf(s.w, up.w + dn.w + cur.z + rt   , m.w);
    return nv;
}

template<int T, int FINAL>
__global__ __launch_bounds__(MT_THR, 6) void lap_march(
    const float* __restrict__ Vin, const uint32_t* __restrict__ packed,
    float* __restrict__ Vout)
{
    __shared__ float4 bnd[2][MT_NSTRIP][2][32];   // parity x strip x {top,bot} x col = 48 KB
    const int tid   = threadIdx.x;
    const int c     = tid & 31;            // float4-column
    const int strip = tid >> 5;            // 4-row strip
    const int o0 = blockIdx.x * MT_OW;
    const int r0 = blockIdx.y * MT_OH;
    const int gc  = o0 - MT_HH + 4*c;
    const int grb = r0 - MT_HV + 4*strip;

    // ---- stage: global -> registers; decode packed -> (s, m) ----
    float4 v0,v1,v2,v3, s0,s1,s2,s3, m0,m1,m2,m3;
    {
        auto loadrow = [&](int gr, float4& vv, float4& ss, float4& mm) {
            const int rr = gr < 0 ? 0 : (gr > RES-1 ? RES-1 : gr);
            const size_t base = (size_t)rr * RES;
            uint4 pp;
            if ((unsigned)gc <= (unsigned)(RES-4)) {   // gc aligned, in-image
                vv = *(const float4*)(Vin + base + gc);
                pp = *(const uint4*)(packed + base + gc);
            } else {
#pragma unroll
                for (int e = 0; e < 4; ++e) {
                    int cc = gc + e; cc = cc < 0 ? 0 : (cc > RES-1 ? RES-1 : cc);
                    ((float*)&vv)[e]    = Vin   [base + cc];
                    ((uint32_t*)&pp)[e] = packed[base + cc];
                }
            }
            mdecode(pp, ss, mm);
        };
        loadrow(grb + 0, v0, s0, m0);
        loadrow(grb + 1, v1, s1, m1);
        loadrow(grb + 2, v2, s2, m2);
        loadrow(grb + 3, v3, s3, m3);
    }

    // ---- T steps, 1 barrier each (parity-dbuf boundary-row exchange) ----
    for (int st = 1; st <= T; ++st) {
        const int par = st & 1;
        bnd[par][strip][0][c] = v0;        // strip's top row (old values)
        bnd[par][strip][1][c] = v3;        // strip's bottom row
        __syncthreads();
        const int sa = strip > 0             ? strip - 1 : 0;            // clamped:
        const int sb = strip < MT_NSTRIP - 1 ? strip + 1 : MT_NSTRIP-1;  // edge garbage OK
        const float4 above = bnd[par][sa][1][c];
        const float4 below = bnd[par][sb][0][c];
        const float4 t0 = v0, t1 = v1, t2 = v2;   // old values for next row's `up`
        v0 = jrow2(above, v1,    v0, s0, m0, grb + 0, gc);
        v1 = jrow2(t0,    v2,    v1, s1, m1, grb + 1, gc);
        v2 = jrow2(t1,    v3,    v2, s2, m2, grb + 2, gc);
        v3 = jrow2(t2,    below, v3, s3, m3, grb + 3, gc);
    }

    // ---- store output region (cols c in [3,29) = [o0, o0+104)) ----
    if (c >= 3 && c < 29 && gc < RES) {
#define STORE_ROW(J, VV, SS)                                                   \
        {   const int gr = grb + (J);                                          \
            if (gr >= r0 && gr < r0 + MT_OH && gr < RES) {                     \
                float4 o = VV;                                                 \
                if (FINAL) {                                                   \
                    o.x = ((SS).x == 0.f) ? o.x : (o.x >= 1.0f ? 0.95f : o.x); \
                    o.y = ((SS).y == 0.f) ? o.y : (o.y >= 1.0f ? 0.95f : o.y); \
                    o.z = ((SS).z == 0.f) ? o.z : (o.z >= 1.0f ? 0.95f : o.z); \
                    o.w = ((SS).w == 0.f) ? o.w : (o.w >= 1.0f ? 0.95f : o.w); \
                }                                                              \
                *(float4*)(Vout + (size_t)gr * RES + gc) = o;                  \
            }                                                                  \
        }
        STORE_ROW(0, v0, s0)
        STORE_ROW(1, v1, s1)
        STORE_ROW(2, v2, s2)
        STORE_ROW(3, v3, s3)
#undef STORE_ROW
    }
}

// ================= precompute: packed field + V0 (unchanged) =================
#define PB_OW 64
#define PB_OH 64
#define PB_HH 8
#define PB_HV 5
#define PB_IW (PB_OW + 2*PB_HH)   // 80
#define PB_IH (PB_OH + 2*PB_HV)   // 74
#define PB_NF4 (PB_IW/4)          // 20
#define PB_NSLOT (PB_NF4*PB_IH)   // 1480
#define PB_THR 512
#define PB_LDSW 84
#define PB_HLDSW 68

__global__ __launch_bounds__(PB_THR, 6) void lap_precompute(
    const float* __restrict__ x, const float* __restrict__ bt,
    const float* __restrict__ bc, const float* __restrict__ C,
    float* __restrict__ V0, uint32_t* __restrict__ packed)
{
    __shared__ float ob[PB_IH * PB_LDSW];   // 24.9 KB
    __shared__ float hs[PB_IH * PB_HLDSW];  // 20.1 KB
    const int tid = threadIdx.x;
    const int r0 = blockIdx.y * PB_OH, c0 = blockIdx.x * PB_OW;

    for (int idx = tid; idx < PB_NSLOT; idx += PB_THR) {
        const int lrow = idx / PB_NF4;
        const int lcol4 = idx - lrow * PB_NF4;
        const int gr = r0 - PB_HV + lrow;
        const int gc = c0 - PB_HH + lcol4 * 4;
        float4 o = {0.f,0.f,0.f,0.f};
        if (gr >= 0 && gr < RES) {
            if (gc >= 0 && gc + 3 < RES) {
                const float4 b = *(const float4*)(bt + (size_t)gr*RES + gc);
                const float4 w = *(const float4*)(bc + (size_t)gr*RES + gc);
                o.x = (b.x == 1.f && w.x > 0.f) ? w.x : 0.f;
                o.y = (b.y == 1.f && w.y > 0.f) ? w.y : 0.f;
                o.z = (b.z == 1.f && w.z > 0.f) ? w.z : 0.f;
                o.w = (b.w == 1.f && w.w > 0.f) ? w.w : 0.f;
            } else {
#pragma unroll
                for (int e = 0; e < 4; ++e) {
                    const int cc = gc + e;
                    if (cc >= 0 && cc < RES) {
                        const float b = bt[(size_t)gr*RES + cc];
                        const float w = bc[(size_t)gr*RES + cc];
                        ((float*)&o)[e] = (b == 1.f && w > 0.f) ? w : 0.f;
                    }
                }
            }
        }
        *(float4*)(&ob[lrow*PB_LDSW + lcol4*4]) = o;
    }
    __syncthreads();

    for (int idx = tid; idx < PB_IH * 16; idx += PB_THR) {
        const int lrow = idx >> 4;
        const int j4 = (idx & 15) << 2;
        const float* row = &ob[lrow * PB_LDSW];
        const float4 a0 = *(const float4*)(row + j4);
        const float4 a1 = *(const float4*)(row + j4 + 4);
        const float4 a2 = *(const float4*)(row + j4 + 8);
        const float4 a3 = *(const float4*)(row + j4 + 12);
        const float4 a4 = *(const float4*)(row + j4 + 16);
        const float common = a1.z + a1.w + a2.x + a2.y + a2.z + a2.w + a3.x + a3.y;
        float4 s;
        s.x = common + a0.w + a1.x + a1.y;
        s.y = common + a1.x + a1.y + a3.z;
        s.z = common + a1.y + a3.z + a3.w;
        s.w = common + a3.z + a3.w + a4.x;
        *(float4*)(&hs[lrow * PB_HLDSW + j4]) = s;
    }
    __syncthreads();

    for (int idx = tid; idx < PB_OH * 16; idx += PB_THR) {
        const int i = idx >> 4;
        const int j4 = (idx & 15) << 2;
        float sx=0.f, sy=0.f, sz=0.f, sw=0.f;
#pragma unroll
        for (int d = 0; d < 11; ++d) {
            const float4 h = *(const float4*)(&hs[(i + d) * PB_HLDSW + j4]);
            sx += h.x; sy += h.y; sz += h.z; sw += h.w;
        }
        const int gr = r0 + i, gc = c0 + j4;
        const size_t g = (size_t)gr * RES + gc;
        const float4 xx  = *(const float4*)(x  + g);
        const float4 cc  = *(const float4*)(C  + g);
        const float4 btv = *(const float4*)(bt + g);
        const float4 bcv = *(const float4*)(bc + g);
        float4 v0; uint4 pko;
        const float es[4] = {sx, sy, sz, sw};
#pragma unroll
        for (int e = 0; e < 4; ++e) {
            const float cpos = fmaxf(((const float*)&cc)[e], 0.f);
            const bool interior = (((const float*)&btv)[e] == 0.0f);
            const float Cc = cpos + es[e] * (1.0f / 121.0f);
            const float bce = ((const float*)&bcv)[e];
            ((uint32_t*)&pko)[e] = interior ? __float_as_uint(Cc)
                                           : (__float_as_uint(bce) | 0x80000000u);
            ((float*)&v0)[e] = interior ? ((const float*)&xx)[e] : bce;
        }
        *(uint4*)(packed + g) = pko;
        *(float4*)(V0 + g) = v0;
    }
}

// ================= C_pos output =================
__global__ __launch_bounds__(256) void lap_cpos(
    const float* __restrict__ C, float* __restrict__ out2)
{
    const int idx = (blockIdx.x * 256 + threadIdx.x) * 4;
    const float4 c = *(const float4*)(C + idx);
    float4 o;
    o.x = fmaxf(c.x, 0.f); o.y = fmaxf(c.y, 0.f);
    o.z = fmaxf(c.z, 0.f); o.w = fmaxf(c.w, 0.f);
    *(float4*)(out2 + idx) = o;
}

extern "C" void kernel_launch(void* const* d_in, const int* in_sizes, int n_in,
                              void* d_out, int out_size, void* d_ws, size_t ws_size,
                              hipStream_t stream) {
    const float* x  = (const float*)d_in[0];
    const float* bt = (const float*)d_in[1];
    const float* bc = (const float*)d_in[2];
    const float* C  = (const float*)d_in[3];

    float*    out1   = (float*)d_out;                        // V ping / final out
    uint32_t* packed = (uint32_t*)((float*)d_out + N_CELLS); // packed field (until cpos)
    float*    vb     = (float*)d_ws;                         // V pong (64 MB)

    dim3 gP(RES / PB_OW, RES / PB_OH);
    lap_precompute<<<gP, PB_THR, 0, stream>>>(x, bt, bc, C, out1, packed);

    dim3 gM(MT_GX, MT_GY);   // 40 x 57, partial edge tiles masked
    lap_march<10, 0><<<gM, MT_THR, 0, stream>>>(out1, packed, vb);
    lap_march<10, 1><<<gM, MT_THR, 0, stream>>>(vb, packed, out1);

    lap_cpos<<<N_CELLS / 1024, 256, 0, stream>>>(C, (float*)d_out + N_CELLS);
}